// Round 1
// baseline (1181.615 us; speedup 1.0000x reference)
//
#include <hip/hip_runtime.h>
#include <hip/hip_bf16.h>
#include <stdint.h>

// Problem constants
#define TOKENS 4096
#define DM     512
#define VOCAB  128000
#define BN     128                 // vocab rows per block (resident in LDS)
#define BM     128                 // token tile
#define BK     128                 // k chunk staged per barrier
#define NCHUNK (VOCAB / BN)        // 1000
#define NTILE  (TOKENS / BM)       // 32

// ws layout (needs ~20.6 MB)
#define XBF_OFF  0
#define PART_OFF (TOKENS * DM * 2)                       // 4,194,304
#define T_OFF    (PART_OFF + NCHUNK * TOKENS * 4)        // +16,384,000
#define LDS_BYTES (BN * DM * 2 + BM * BK * 2)            // 131072 + 32768 = 163840

typedef __attribute__((ext_vector_type(8))) short short8;
typedef __attribute__((ext_vector_type(4))) float f32x4;

__device__ __forceinline__ unsigned short f2bf(float f) {
  unsigned u;
  __builtin_memcpy(&u, &f, 4);
  u += 0x7fffu + ((u >> 16) & 1u);        // round-to-nearest-even
  return (unsigned short)(u >> 16);
}

// ---------------- stage 0: x fp32 -> bf16, zero the output scalar ----------
__global__ void cvt_x_kernel(const float* __restrict__ x,
                             unsigned short* __restrict__ xb,
                             float* __restrict__ out) {
  int i = (blockIdx.x * 256 + threadIdx.x) * 4;   // 2048 blocks * 256 * 4 = 2,097,152
  float4 v = *(const float4*)(x + i);
  ushort4 o;
  o.x = f2bf(v.x); o.y = f2bf(v.y); o.z = f2bf(v.z); o.w = f2bf(v.w);
  *(ushort4*)(xb + i) = o;
  if (blockIdx.x == 0 && threadIdx.x == 0) out[0] = 0.0f;
}

// ---------------- stage 1: W-chunk-resident GEMM + per-chunk sumexp --------
// block c: W rows [c*128, c*128+128) resident in LDS (bf16, kb-XOR swizzled).
// Loops all 32 token tiles; writes part[c*TOKENS + token] = sum_n exp(logit).
__global__ __launch_bounds__(256, 1) void gemm_sumexp_kernel(
    const float* __restrict__ W, const unsigned short* __restrict__ Xb,
    float* __restrict__ part) {
  extern __shared__ char smem[];
  short8* Wl  = (short8*)smem;                    // [BN][64] 16B-blocks, swizzled
  short8* Xl  = (short8*)(smem + BN * DM * 2);    // [BM][16] 16B-blocks, swizzled
  uint4*  Xlw = (uint4*)(smem + BN * DM * 2);     // write view of Xl
  float*  sc  = (float*)(smem + BN * DM * 2);     // epilogue scratch (aliases Xl)

  const int tid  = threadIdx.x;
  const int c    = blockIdx.x;
  const int lane = tid & 63;
  const int wave = tid >> 6;
  const int wn   = wave >> 1;        // vocab half (0/1)
  const int wm   = wave & 1;         // token half (0/1)
  const int ln   = lane & 15;
  const int quad = lane >> 4;
  const int sA   = ln & 7;           // swizzle key (row&7 == ln&7 here)

  // ---- load W chunk -> LDS bf16 (once per block; fully coalesced 32B/lane)
  {
    const float* Wg = W + (size_t)c * BN * DM;
    #pragma unroll
    for (int it = 0; it < 32; ++it) {
      int b = it * 256 + tid;                 // 0..8191 16B-blocks
      int n = b >> 6, kb = b & 63;
      const float* p = Wg + n * DM + kb * 8;
      float4 v0 = *(const float4*)p;
      float4 v1 = *(const float4*)(p + 4);
      short8 s;
      s[0] = (short)f2bf(v0.x); s[1] = (short)f2bf(v0.y);
      s[2] = (short)f2bf(v0.z); s[3] = (short)f2bf(v0.w);
      s[4] = (short)f2bf(v1.x); s[5] = (short)f2bf(v1.y);
      s[6] = (short)f2bf(v1.z); s[7] = (short)f2bf(v1.w);
      Wl[n * 64 + (kb ^ (n & 7))] = s;
    }
  }

  #pragma unroll 1
  for (int t = 0; t < NTILE; ++t) {
    f32x4 acc[4][4];
    #pragma unroll
    for (int i = 0; i < 4; ++i)
      #pragma unroll
      for (int j = 0; j < 4; ++j)
        acc[i][j] = f32x4{0.f, 0.f, 0.f, 0.f};

    #pragma unroll 1
    for (int kc = 0; kc < DM / BK; ++kc) {
      __syncthreads();                        // protect Xl/sc from previous use
      // stage x chunk [BM][BK] bf16 -> LDS (swizzled)
      #pragma unroll
      for (int it = 0; it < 8; ++it) {
        int b = it * 256 + tid;               // 0..2047 16B-blocks
        int m = b >> 4, kb = b & 15;
        uint4 v = *(const uint4*)(Xb + (size_t)(t * BM + m) * DM + kc * BK + kb * 8);
        Xlw[m * 16 + (kb ^ (m & 7))] = v;
      }
      __syncthreads();
      #pragma unroll
      for (int ks = 0; ks < BK / 32; ++ks) {
        short8 af[4], bfr[4];
        const int kbA = kc * 16 + ks * 4 + quad;    // W kb index (of 64)
        const int kbB = ks * 4 + quad;              // x kb index (of 16)
        #pragma unroll
        for (int i = 0; i < 4; ++i) {
          int row = wn * 64 + i * 16 + ln;
          af[i] = Wl[row * 64 + (kbA ^ sA)];
        }
        #pragma unroll
        for (int j = 0; j < 4; ++j) {
          int m = wm * 64 + j * 16 + ln;
          bfr[j] = Xl[m * 16 + (kbB ^ sA)];
        }
        #pragma unroll
        for (int i = 0; i < 4; ++i)
          #pragma unroll
          for (int j = 0; j < 4; ++j)
            acc[i][j] = __builtin_amdgcn_mfma_f32_16x16x32_bf16(
                af[i], bfr[j], acc[i][j], 0, 0, 0);
      }
    }
    __syncthreads();   // last chunk's Xl reads done; sc may now alias it

    // epilogue: per-token sum of exp over this block's 128 vocab rows.
    // acc[i][j][r]: token = wm*64+j*16+ln (fixed per lane per j),
    //               vocab row = wn*64+i*16+quad*4+r.
    #pragma unroll
    for (int j = 0; j < 4; ++j) {
      float e = 0.f;
      #pragma unroll
      for (int i = 0; i < 4; ++i) {
        #pragma unroll
        for (int r = 0; r < 4; ++r) e += __expf(acc[i][j][r]);
      }
      e += __shfl_xor(e, 16, 64);
      e += __shfl_xor(e, 32, 64);
      if (lane < 16) sc[wn * 128 + wm * 64 + j * 16 + lane] = e;
    }
    __syncthreads();
    if (tid < 128)
      part[c * TOKENS + t * BM + tid] = sc[tid] + sc[128 + tid];
    // next iteration's first __syncthreads() protects sc before Xl reuse
  }
}

// ---------------- stage 2a: exact fp32 target scores -----------------------
__global__ void target_dot_kernel(const float* __restrict__ x,
                                  const float* __restrict__ W,
                                  const int* __restrict__ tgt,
                                  float* __restrict__ T) {
  int wave = threadIdx.x >> 6, lane = threadIdx.x & 63;
  int i = blockIdx.x * 4 + wave;                 // 1024 blocks * 4 waves = 4096
  int r = tgt[i];
  const float4* xp = (const float4*)(x + (size_t)i * DM + lane * 8);
  const float4* wp = (const float4*)(W + (size_t)r * DM + lane * 8);
  float4 a0 = xp[0], a1 = xp[1], b0 = wp[0], b1 = wp[1];
  float s = a0.x * b0.x + a0.y * b0.y + a0.z * b0.z + a0.w * b0.w
          + a1.x * b1.x + a1.y * b1.y + a1.z * b1.z + a1.w * b1.w;
  #pragma unroll
  for (int m = 32; m >= 1; m >>= 1) s += __shfl_xor(s, m, 64);
  if (lane == 0) T[i] = s;
}

// ---------------- stage 2b: reduce chunks, loss, total ---------------------
__global__ void reduce_loss_kernel(const float* __restrict__ part,
                                   const float* __restrict__ T,
                                   float* __restrict__ out) {
  __shared__ float red[256];
  int tid = threadIdx.x;
  int tok = blockIdx.x * 64 + (tid & 63);        // 64 blocks * 64 tokens
  int g = tid >> 6;
  float S = 0.f;
  #pragma unroll 5
  for (int cc = g; cc < NCHUNK; cc += 4) S += part[cc * TOKENS + tok];
  red[tid] = S;
  __syncthreads();
  if (tid < 64) {
    float Sa = red[tid] + red[64 + tid] + red[128 + tid] + red[192 + tid];
    float loss = __logf(Sa) - T[tok];            // = m + log s - t (max-free form)
    #pragma unroll
    for (int m = 32; m >= 1; m >>= 1) loss += __shfl_xor(loss, m, 64);
    if (tid == 0) atomicAdd(out, loss);
  }
}

extern "C" void kernel_launch(void* const* d_in, const int* in_sizes, int n_in,
                              void* d_out, int out_size, void* d_ws, size_t ws_size,
                              hipStream_t stream) {
  const float* x   = (const float*)d_in[0];
  const float* W   = (const float*)d_in[1];
  const int*   tgt = (const int*)d_in[2];
  float* out = (float*)d_out;

  unsigned short* xb   = (unsigned short*)((char*)d_ws + XBF_OFF);
  float*          part = (float*)((char*)d_ws + PART_OFF);
  float*          T    = (float*)((char*)d_ws + T_OFF);

  // allow 160 KB dynamic LDS (idempotent; host-side, safe under graph capture)
  hipFuncSetAttribute(reinterpret_cast<const void*>(gemm_sumexp_kernel),
                      hipFuncAttributeMaxDynamicSharedMemorySize, LDS_BYTES);

  cvt_x_kernel<<<TOKENS * DM / (256 * 4), 256, 0, stream>>>(x, xb, out);
  gemm_sumexp_kernel<<<NCHUNK, 256, LDS_BYTES, stream>>>(W, xb, part);
  target_dot_kernel<<<TOKENS / 4, 256, 0, stream>>>(x, W, tgt, T);
  reduce_loss_kernel<<<TOKENS / 64, 256, 0, stream>>>(part, T, out);
}